// Round 11
// baseline (446.938 us; speedup 1.0000x reference)
//
#include <hip/hip_runtime.h>
#include <math.h>

#define BB   256     // batch
#define NN0  400     // nodes at layer 1
#define NE   79800   // NN0*(NN0-1)/2
#define EPSF 1e-5f

// ---------- device helpers ----------
__device__ __forceinline__ int tri_e(int a, int c) {  // a<c, upper-tri flat index
  return a*(NN0-1) - ((a*(a-1))>>1) + (c - a - 1);
}

__device__ __forceinline__ size_t PRI(int b, int ti, int tj, int r) {
  return (((size_t)b*7 + ti)*7 + tj)*64 + r;
}

__device__ __forceinline__ float wave_sum(float v) {
  #pragma unroll
  for (int o = 32; o > 0; o >>= 1) v += __shfl_xor(v, o, 64);
  return v;
}

// descending bitonic sort (score desc, idx asc == jax.lax.top_k order)
__device__ __forceinline__ void bitonic_desc(float* sc, int* si, int P) {
  const int tid = threadIdx.x;
  const int nt = blockDim.x;
  for (int k = 2; k <= P; k <<= 1) {
    for (int j = k >> 1; j > 0; j >>= 1) {
      __syncthreads();
      for (int i = tid; i < P; i += nt) {
        int ixj = i ^ j;
        if (ixj > i) {
          float a = sc[i], c = sc[ixj];
          int ai = si[i], ci = si[ixj];
          bool bef = (a > c) || (a == c && ai < ci);
          bool sw = ((i & k) == 0) ? !bef : bef;
          if (sw) { sc[i] = c; sc[ixj] = a; si[i] = ci; si[ixj] = ai; }
        }
      }
    }
  }
  __syncthreads();
}

// ---------- K1: dense symmetric tri-matvec partials (NO atomics) ----------
__global__ __launch_bounds__(256) void k_tri_mv(
    const float* __restrict__ data,
    const float* __restrict__ pr_in, const float* __restrict__ pc_in,
    float* __restrict__ pr, float* __restrict__ pc) {
  __shared__ float tile[64][65];
  __shared__ float dI[64], dJ[64];
  const int xcd = blockIdx.x & 7, slot = blockIdx.x >> 3;   // 8 x 224
  const int b = xcd*32 + slot/7, q0 = slot % 7;
  const int tid = threadIdx.x;
  const int wave = tid >> 6, lane = tid & 63;
  const float* __restrict__ drow = data + (size_t)b*NE;
  int ti_a[4], tj_a[4];
  #pragma unroll
  for (int u = 0; u < 4; ++u) {
    int t = q0 + u*7;
    int ti = 0, rem = t;
    while (rem >= 7 - ti) { rem -= 7 - ti; ++ti; }
    ti_a[u] = ti; tj_a[u] = ti + rem;
  }
  float vreg[16];
  float rI = 0.f, rJ = 0.f;
  auto issue = [&](int u) {
    const int i0 = ti_a[u]*64, j0 = tj_a[u]*64;
    const int ni = min(64, NN0 - i0), nj = min(64, NN0 - j0);
    #pragma unroll
    for (int k = 0; k < 16; ++k) {
      const int rr = wave*16 + k;
      const int i = i0 + rr, j = j0 + lane;
      vreg[k] = 0.f;
      if (rr < ni && lane < nj && j > i) vreg[k] = drow[tri_e(i, j)];
    }
    if (pr_in) {
      if (tid < 64) {
        float a = 0.f;
        if (tid < ni) {
          const int tt = ti_a[u], r = tid;
          float acc = 1.f;
          for (int tj = tt; tj < 7; ++tj) acc += pr_in[PRI(b, tt, tj, r)];
          for (int ts = 0; ts <= tt; ++ts) acc += pc_in[PRI(b, ts, tt, r)];
          a = rsqrtf(acc);
        }
        rI = a;
      } else if (tid < 128) {
        const int c = tid - 64;
        float a = 0.f;
        if (c < nj) {
          const int tt = tj_a[u], r = c;
          float acc = 1.f;
          for (int tj = tt; tj < 7; ++tj) acc += pr_in[PRI(b, tt, tj, r)];
          for (int ts = 0; ts <= tt; ++ts) acc += pc_in[PRI(b, ts, tt, r)];
          a = rsqrtf(acc);
        }
        rJ = a;
      }
    } else {
      if (tid < 64) rI = (tid < ni) ? 1.f : 0.f;
      else if (tid < 128) rJ = (tid - 64 < nj) ? 1.f : 0.f;
    }
  };
  issue(0);
  #pragma unroll 1
  for (int u = 0; u < 4; ++u) {
    const int ti = ti_a[u], tj = tj_a[u];
    if (u) __syncthreads();
    #pragma unroll
    for (int k = 0; k < 16; ++k) tile[wave*16 + k][lane] = vreg[k];
    if (tid < 64) dI[tid] = rI;
    else if (tid < 128) dJ[tid-64] = rJ;
    __syncthreads();
    if (u + 1 < 4) issue(u + 1);
    {
      const int r = tid >> 2, q = tid & 3;
      float s = 0.f;
      #pragma unroll
      for (int c = 0; c < 16; ++c) s += tile[r][q*16 + c] * dJ[q*16 + c];
      s += __shfl_xor(s, 1, 64);
      s += __shfl_xor(s, 2, 64);
      if (q == 0) pr[PRI(b, ti, tj, r)] = s;
    }
    {
      const int c = tid >> 2, q = tid & 3;
      float s = 0.f;
      #pragma unroll
      for (int r = 0; r < 16; ++r) s += tile[q*16 + r][c] * dI[q*16 + r];
      s += __shfl_xor(s, 1, 64);
      s += __shfl_xor(s, 2, 64);
      if (q == 0) pc[PRI(b, ti, tj, c)] = s;
    }
  }
}

// ---------- K2: reduce deg & s partials -> s1, + BN stats via global atomics ----------
__global__ __launch_bounds__(256) void k_sfin_stats_red(
    const float* __restrict__ pr, const float* __restrict__ pc,
    const float* __restrict__ pr2, const float* __restrict__ pc2,
    const float* __restrict__ W1, const float* __restrict__ b1,
    float* __restrict__ s1, float* __restrict__ acc1) {
  __shared__ float sl[256];
  __shared__ float st[64];
  __shared__ float w1s[32], b1s[32];
  const int tid = threadIdx.x;
  const int i = blockIdx.x*256 + tid;
  if (tid < 32) { w1s[tid] = W1[tid]; b1s[tid] = b1[tid]; }
  if (tid < 64) st[tid] = 0.f;
  const int b = i / NN0, n = i % NN0;
  const int t = n >> 6, r = n & 63;
  float dacc = 1.f, sacc = 0.f;
  for (int tj = t; tj < 7; ++tj) { dacc += pr[PRI(b, t, tj, r)]; sacc += pr2[PRI(b, t, tj, r)]; }
  for (int ti = 0; ti <= t; ++ti) { dacc += pc[PRI(b, ti, t, r)]; sacc += pc2[PRI(b, ti, t, r)]; }
  const float d = rsqrtf(dacc);
  const float s = d * (d + sacc);
  s1[i] = s;
  sl[tid] = s;
  __syncthreads();
  const int f = tid & 31, sub = tid >> 5;
  const float w = w1s[f], bb = b1s[f];
  float S = 0.f, Q = 0.f;
  #pragma unroll
  for (int k = 0; k < 32; ++k) {
    const float ss = sl[sub*32 + k];
    const float h = fmaxf(ss*w + bb, 0.f);
    S += h; Q += h*h;
  }
  atomicAdd(&st[f], S);
  atomicAdd(&st[32+f], Q);
  __syncthreads();
  if (tid < 64) atomicAdd(&acc1[tid], st[tid]);
}

// ---------- K3: inline BN-coeffs + layer-1 score + top-200 + Y2 = X2@W2 + perm ----------
__global__ __launch_bounds__(512) void k_top1(
    const float* __restrict__ s1, const float* __restrict__ acc1,
    const float* __restrict__ W1, const float* __restrict__ b1,
    const float* __restrict__ g1, const float* __restrict__ be1,
    const float* __restrict__ p1, const float* __restrict__ W2,
    int* __restrict__ nodes2, int* __restrict__ sperm2, float* __restrict__ Y2) {
  __shared__ float sc[512]; __shared__ int si[512];
  __shared__ float sS[NN0];
  __shared__ float tvs[200];
  __shared__ int nds_l[200];
  __shared__ float w1s[32], b1s[32], cfs[32], scs[32], shs[32];
  __shared__ __align__(16) float hp[6400];
  __shared__ float c0s;
  const int tid = threadIdx.x;
  const int b = (blockIdx.x & 7)*32 + (blockIdx.x >> 3);   // XCD-swizzle
  if (tid < 32) { w1s[tid] = W1[tid]; b1s[tid] = b1[tid]; }
  if (tid < 64) {                       // inlined fin1
    float scale = 0.f, shift = 0.f, pv = 0.f;
    if (tid < 32) {
      const float S = acc1[tid], Q = acc1[32 + tid];
      const float N = 102400.f;
      const float mu = S / N;
      const float var = Q / N - mu*mu;
      const float inv = rsqrtf(var + EPSF);
      scale = inv * g1[tid];
      shift = be1[tid] - mu * scale;
      pv = p1[tid];
    }
    const float pn = sqrtf(wave_sum(pv*pv));
    if (tid < 32) { scs[tid] = scale; shs[tid] = shift; cfs[tid] = scale*pv/pn; }
    float u = (tid < 32) ? shift*pv/pn : 0.f;
    u = wave_sum(u);
    if (tid == 0) c0s = u;
  }
  __syncthreads();
  const float c0 = c0s;
  {
    const int i = tid;
    if (i < NN0) {
      const float s = s1[(size_t)b*NN0 + i];
      sS[i] = s;
      float sco = c0;
      #pragma unroll
      for (int f = 0; f < 32; ++f) sco += fmaxf(s*w1s[f] + b1s[f], 0.f) * cfs[f];
      sc[i] = sco; si[i] = i;
    } else { sc[i] = -INFINITY; si[i] = 0x7fffffff; }
  }
  bitonic_desc(sc, si, 512);
  for (int k = tid; k < 200; k += 512) {
    tvs[k] = tanhf(sc[k]);
    nds_l[k] = si[k];
    nodes2[b*200 + k] = si[k];
  }
  __syncthreads();
  for (int o = tid; o < 6400; o += 512) {
    const int k = o >> 5, f = o & 31;
    const float s = sS[nds_l[k]];
    const float h = fmaxf(s*w1s[f] + b1s[f], 0.f);
    hp[o] = (h*scs[f] + shs[f]) * tvs[k];
  }
  __syncthreads();
  // Y2 = X2 @ W2 (unscaled; dis2 folded into A2')
  {
    const int g = tid & 63;
    float wr[32];
    #pragma unroll
    for (int f = 0; f < 32; ++f) wr[f] = W2[f*64 + g];
    for (int o = tid; o < 12800; o += 512) {
      const int k = o >> 6;
      float acc = 0.f;
      #pragma unroll
      for (int c4 = 0; c4 < 8; ++c4) {
        const float4 x4 = *(const float4*)&hp[(k<<5) + (c4<<2)];
        acc += x4.x*wr[c4*4] + x4.y*wr[c4*4+1] + x4.z*wr[c4*4+2] + x4.w*wr[c4*4+3];
      }
      Y2[(size_t)b*12800 + o] = acc;
    }
  }
  __syncthreads();
  if (tid < 256) {
    sc[tid] = (tid < 200) ? -(float)nds_l[tid] : -INFINITY;
    si[tid] = (tid < 200) ? tid : 0x7fffffff;
  }
  bitonic_desc(sc, si, 256);
  if (tid < 200) sperm2[b*200 + tid] = si[tid];
}

// ---------- K4: gather A2 (sorted-id order, XCD-swizzled), row-scaled by dis2 ----------
__global__ __launch_bounds__(256) void k_gatherA2(
    const float* __restrict__ data, const int* __restrict__ nodes2,
    const int* __restrict__ sperm2, float* __restrict__ A2, float* __restrict__ dis2) {
  __shared__ int nds[200], sp[200], sn[200];
  __shared__ float rowbuf[4][200];
  const int idx = blockIdx.x;
  const int r9 = idx >> 3;
  const int b = (idx & 7)*32 + r9/50;
  const int rg = r9 % 50;
  const int tid = threadIdx.x;
  if (tid < 200) { nds[tid] = nodes2[b*200 + tid]; sp[tid] = sperm2[b*200 + tid]; }
  __syncthreads();
  if (tid < 200) sn[tid] = nds[sp[tid]];
  __syncthreads();
  const int wave = tid >> 6, lane = tid & 63;
  const int i = rg*4 + wave;
  const int ni = nds[i];
  const float* __restrict__ drow = data + (size_t)b*NE;
  float accd = 0.f;
  for (int jj = lane; jj < 200; jj += 64) {
    const int sj = sn[jj];
    float v = 0.f;
    if (sj != ni) {
      const int a = min(ni, sj), c = max(ni, sj);
      v = drow[tri_e(a, c)];
    }
    rowbuf[wave][sp[jj]] = v;
    accd += v;
  }
  __syncthreads();
  accd = wave_sum(accd);
  const float dd = rsqrtf(1.f + accd);
  for (int j = lane; j < 200; j += 64)
    A2[((size_t)b*200 + i)*200 + j] = rowbuf[wave][j] * dd;   // dis-row-scaled
  if (lane == 0) dis2[b*200 + i] = dd;
}

// ---------- K5: conv2 as tiled GEMM, 8x8 register tiles, no readlane ----------
// grid = BB (XCD-swizzled), 1 batch per block. Thread (tr<25, tc<8) owns
// rows [8tr,8tr+8) x feats [8tc,8tc+8). tc is fastest -> wave A-reads are
// 8 addrs x 8-lane broadcast (2-way banks = free). A2' (row-scaled) staged
// in LDS in 25-j chunks, register-double-buffered. z = raw Y2 from global.
// acc[r][f] = sum_j A2'[j][r] * Y2[j][f]  (A2'[j][r] = A[j][r]*d_j).
__global__ __launch_bounds__(256) void k_conv2(
    const float* __restrict__ A2, const float* __restrict__ Y2,
    const float* __restrict__ dis2, const float* __restrict__ b2,
    float* __restrict__ h2g, float* __restrict__ acc2g) {
  __shared__ __align__(16) float As[5000];   // 20 KB: 25 j x 200 r
  __shared__ float dsb[200];
  __shared__ float st[128];
  const int tid = threadIdx.x;
  const int b = (blockIdx.x & 7)*32 + (blockIdx.x >> 3);
  const int tr = tid >> 3, tc = tid & 7;     // tr<25 active
  if (tid < 128) st[tid] = 0.f;
  if (tid < 200) dsb[tid] = dis2[b*200 + tid];
  const float* __restrict__ Ab = A2 + (size_t)b*40000;
  const float* __restrict__ Yb = Y2 + (size_t)b*12800;
  // stage chunk 0 (25 j x 200 r = 5000 floats = 1250 float4)
  float4 pf0, pf1, pf2, pf3;
  float4 pf4 = make_float4(0.f, 0.f, 0.f, 0.f);
  {
    pf0 = *(const float4*)&Ab[(size_t)(tid)*4];
    pf1 = *(const float4*)&Ab[(size_t)(tid + 256)*4];
    pf2 = *(const float4*)&Ab[(size_t)(tid + 512)*4];
    pf3 = *(const float4*)&Ab[(size_t)(tid + 768)*4];
    if (tid < 226) pf4 = *(const float4*)&Ab[(size_t)(tid + 1024)*4];
  }
  *(float4*)&As[tid*4] = pf0;
  *(float4*)&As[(tid + 256)*4] = pf1;
  *(float4*)&As[(tid + 512)*4] = pf2;
  *(float4*)&As[(tid + 768)*4] = pf3;
  if (tid < 226) *(float4*)&As[(tid + 1024)*4] = pf4;
  __syncthreads();
  float acc[8][8];
  #pragma unroll
  for (int i = 0; i < 8; ++i)
    #pragma unroll
    for (int k = 0; k < 8; ++k) acc[i][k] = 0.f;
  #pragma unroll 1
  for (int c = 0; c < 8; ++c) {
    // prefetch chunk c+1 into registers (overlaps compute)
    if (c < 7) {
      const float* __restrict__ src = Ab + (size_t)(c + 1)*5000;
      pf0 = *(const float4*)&src[(size_t)(tid)*4];
      pf1 = *(const float4*)&src[(size_t)(tid + 256)*4];
      pf2 = *(const float4*)&src[(size_t)(tid + 512)*4];
      pf3 = *(const float4*)&src[(size_t)(tid + 768)*4];
      if (tid < 226) pf4 = *(const float4*)&src[(size_t)(tid + 1024)*4];
    }
    // compute chunk c
    if (tr < 25) {
      #pragma unroll 1
      for (int js = 0; js < 25; ++js) {
        const int j = c*25 + js;
        float af[8], zf[8];
        *(float4*)&af[0] = *(const float4*)&As[js*200 + tr*8];
        *(float4*)&af[4] = *(const float4*)&As[js*200 + tr*8 + 4];
        *(float4*)&zf[0] = *(const float4*)&Yb[(size_t)j*64 + tc*8];
        *(float4*)&zf[4] = *(const float4*)&Yb[(size_t)j*64 + tc*8 + 4];
        #pragma unroll
        for (int i = 0; i < 8; ++i)
          #pragma unroll
          for (int k = 0; k < 8; ++k)
            acc[i][k] = fmaf(af[i], zf[k], acc[i][k]);
      }
    }
    __syncthreads();
    if (c < 7) {
      *(float4*)&As[tid*4] = pf0;
      *(float4*)&As[(tid + 256)*4] = pf1;
      *(float4*)&As[(tid + 512)*4] = pf2;
      *(float4*)&As[(tid + 768)*4] = pf3;
      if (tid < 226) *(float4*)&As[(tid + 1024)*4] = pf4;
      __syncthreads();
    }
  }
  // epilogue
  if (tr < 25) {
    float blv[8];
    *(float4*)&blv[0] = *(const float4*)&b2[tc*8];
    *(float4*)&blv[4] = *(const float4*)&b2[tc*8 + 4];
    float ssl[8], qql[8];
    #pragma unroll
    for (int k = 0; k < 8; ++k) { ssl[k] = 0.f; qql[k] = 0.f; }
    #pragma unroll
    for (int i = 0; i < 8; ++i) {
      const int r = tr*8 + i;
      const float d = dsb[r];
      float yv[8], hv[8];
      *(float4*)&yv[0] = *(const float4*)&Yb[(size_t)r*64 + tc*8];
      *(float4*)&yv[4] = *(const float4*)&Yb[(size_t)r*64 + tc*8 + 4];
      #pragma unroll
      for (int k = 0; k < 8; ++k) {
        const float h = fmaxf(d*acc[i][k] + d*(d*yv[k]) + blv[k], 0.f);
        hv[k] = h; ssl[k] += h; qql[k] += h*h;
      }
      *(float4*)&h2g[((size_t)b*200 + r)*64 + tc*8] = *(float4*)&hv[0];
      *(float4*)&h2g[((size_t)b*200 + r)*64 + tc*8 + 4] = *(float4*)&hv[4];
    }
    #pragma unroll
    for (int k = 0; k < 8; ++k) {
      atomicAdd(&st[tc*8 + k], ssl[k]);
      atomicAdd(&st[64 + tc*8 + k], qql[k]);
    }
  }
  __syncthreads();
  if (tid < 128) atomicAdd(&acc2g[tid], st[tid]);
}

// ---------- K6: inline BN-coeffs + layer-2 score + top-100 + Y3 = X3@W3 ----------
__global__ __launch_bounds__(512) void k_top2(
    const float* __restrict__ h2g, const float* __restrict__ acc2,
    const float* __restrict__ g2, const float* __restrict__ be2,
    const float* __restrict__ p2, const float* __restrict__ W3,
    const int* __restrict__ nodes2, int* __restrict__ nodes3,
    float* __restrict__ Y3) {
  __shared__ float sc[256]; __shared__ int si[256];
  __shared__ __align__(16) float xs[6400];
  __shared__ float sc2[64], sh2[64], cf2[64];
  __shared__ float c20s;
  const int tid = threadIdx.x;
  const int b = (blockIdx.x & 7)*32 + (blockIdx.x >> 3);   // XCD-swizzle
  if (tid < 64) {                       // inlined fin2
    const float S = acc2[tid], Q = acc2[64 + tid];
    const float N = 51200.f;
    const float mu = S/N, var = Q/N - mu*mu, inv = rsqrtf(var + EPSF);
    const float scale = inv*g2[tid], shift = be2[tid] - mu*scale;
    const float pv = p2[tid];
    const float pn = sqrtf(wave_sum(pv*pv));
    sc2[tid] = scale; sh2[tid] = shift; cf2[tid] = scale*pv/pn;
    const float u = wave_sum(shift*pv/pn);
    if (tid == 0) c20s = u;
  }
  __syncthreads();
  const int wave = tid >> 6, lane = tid & 63;
  const float cf = cf2[lane];
  const float c20 = c20s;
  for (int i = wave; i < 200; i += 8) {
    float v = h2g[((size_t)b*200 + i)*64 + lane] * cf;
    v = wave_sum(v);
    if (lane == 0) { sc[i] = v + c20; si[i] = i; }
  }
  if (tid >= 200 && tid < 256) { sc[tid] = -INFINITY; si[tid] = 0x7fffffff; }
  bitonic_desc(sc, si, 256);
  const float scale = sc2[lane], shift = sh2[lane];
  for (int o = tid; o < 6400; o += 512) {
    const int k = o >> 6;
    const int idx = si[k];
    const float tv = tanhf(sc[k]);
    xs[o] = (h2g[((size_t)b*200 + idx)*64 + lane] * scale + shift) * tv;
  }
  for (int k = tid; k < 100; k += 512) nodes3[b*100 + k] = nodes2[b*200 + si[k]];
  __syncthreads();
  // Y3 = X3 @ W3 (unscaled; dis3 folded into A3')
  {
    const int g = tid & 127;
    float wr[64];
    #pragma unroll
    for (int f = 0; f < 64; ++f) wr[f] = W3[f*128 + g];
    for (int o = tid; o < 12800; o += 512) {
      const int k = o >> 7;
      float acc = 0.f;
      #pragma unroll
      for (int c4 = 0; c4 < 16; ++c4) {
        const float4 x4 = *(const float4*)&xs[(k<<6) + (c4<<2)];
        acc += x4.x*wr[c4*4] + x4.y*wr[c4*4+1] + x4.z*wr[c4*4+2] + x4.w*wr[c4*4+3];
      }
      Y3[(size_t)b*12800 + o] = acc;
    }
  }
}

// ---------- K7: gather A3 + dis3 (XCD-swizzled), row-scaled by dis3 ----------
__global__ __launch_bounds__(256) void k_gatherA3(
    const float* __restrict__ data, const int* __restrict__ nodes3,
    float* __restrict__ A3, float* __restrict__ dis3) {
  __shared__ int nds[100];
  const int slot = blockIdx.x >> 3;                 // 8 x 800
  const int b = (blockIdx.x & 7)*32 + slot/25, rg = slot % 25;
  const int tid = threadIdx.x;
  if (tid < 100) nds[tid] = nodes3[b*100 + tid];
  __syncthreads();
  const int wave = tid >> 6, lane = tid & 63;
  const int i = rg*4 + wave;
  const int ni = nds[i];
  const float* __restrict__ drow = data + (size_t)b*NE;
  const int j0 = lane, j1 = 64 + lane;
  float v0 = 0.f, v1 = 0.f;
  if (j0 != i) {
    const int nj = nds[j0];
    const int a = min(ni, nj), c = max(ni, nj);
    v0 = drow[tri_e(a, c)];
  }
  if (j1 < 100 && j1 != i) {
    const int nj = nds[j1];
    const int a = min(ni, nj), c = max(ni, nj);
    v1 = drow[tri_e(a, c)];
  }
  const float accd = wave_sum(v0 + v1);
  const float dd = rsqrtf(1.f + accd);
  A3[((size_t)b*100 + i)*100 + j0] = v0 * dd;       // dis-row-scaled
  if (j1 < 100) A3[((size_t)b*100 + i)*100 + j1] = v1 * dd;
  if (lane == 0) dis3[b*100 + i] = dd;
}

// ---------- K8: conv3 as tiled GEMM, 8x8 register tiles ----------
// grid = BB (XCD-swizzled). Thread (tr<13, tc<16) owns rows [8tr, min(8tr+8,100))
// x feats [8tc, 8tc+8). Whole A3' (100x100 = 40KB) staged in LDS once.
// z = raw Y3 from global. acc = sum_j A3'[j][r]*Y3[j][f].
__global__ __launch_bounds__(256) void k_conv3(
    const float* __restrict__ A3, const float* __restrict__ Y3,
    const float* __restrict__ dis3, const float* __restrict__ b3,
    float* __restrict__ h3g, float* __restrict__ acc3g) {
  __shared__ __align__(16) float As[10016];  // 40KB + pad (tr=12 frag overreads 3)
  __shared__ float dsb[100];
  __shared__ float st[256];
  const int tid = threadIdx.x;
  const int b = (blockIdx.x & 7)*32 + (blockIdx.x >> 3);
  const int tr = tid >> 4, tc = tid & 15;    // tr<13 active
  st[tid] = 0.f;
  if (tid < 100) dsb[tid] = dis3[b*100 + tid];
  const float* __restrict__ Ab = A3 + (size_t)b*10000;
  const float* __restrict__ Yb = Y3 + (size_t)b*12800;
  for (int t = tid; t < 2500; t += 256)
    *(float4*)&As[t*4] = *(const float4*)&Ab[(size_t)t*4];
  __syncthreads();
  float acc[8][8];
  #pragma unroll
  for (int i = 0; i < 8; ++i)
    #pragma unroll
    for (int k = 0; k < 8; ++k) acc[i][k] = 0.f;
  if (tr < 13) {
    #pragma unroll 2
    for (int j = 0; j < 100; ++j) {
      float af[8], zf[8];
      *(float4*)&af[0] = *(const float4*)&As[j*100 + tr*8];
      *(float4*)&af[4] = *(const float4*)&As[j*100 + tr*8 + 4];
      *(float4*)&zf[0] = *(const float4*)&Yb[(size_t)j*128 + tc*8];
      *(float4*)&zf[4] = *(const float4*)&Yb[(size_t)j*128 + tc*8 + 4];
      #pragma unroll
      for (int i = 0; i < 8; ++i)
        #pragma unroll
        for (int k = 0; k < 8; ++k)
          acc[i][k] = fmaf(af[i], zf[k], acc[i][k]);
    }
    // epilogue
    float blv[8];
    *(float4*)&blv[0] = *(const float4*)&b3[tc*8];
    *(float4*)&blv[4] = *(const float4*)&b3[tc*8 + 4];
    float ssl[8], qql[8];
    #pragma unroll
    for (int k = 0; k < 8; ++k) { ssl[k] = 0.f; qql[k] = 0.f; }
    #pragma unroll
    for (int i = 0; i < 8; ++i) {
      const int r = tr*8 + i;
      if (r < 100) {
        const float d = dsb[r];
        float yv[8], hv[8];
        *(float4*)&yv[0] = *(const float4*)&Yb[(size_t)r*128 + tc*8];
        *(float4*)&yv[4] = *(const float4*)&Yb[(size_t)r*128 + tc*8 + 4];
        #pragma unroll
        for (int k = 0; k < 8; ++k) {
          const float h = fmaxf(d*acc[i][k] + d*(d*yv[k]) + blv[k], 0.f);
          hv[k] = h; ssl[k] += h; qql[k] += h*h;
        }
        *(float4*)&h3g[((size_t)b*100 + r)*128 + tc*8] = *(float4*)&hv[0];
        *(float4*)&h3g[((size_t)b*100 + r)*128 + tc*8 + 4] = *(float4*)&hv[4];
      }
    }
    #pragma unroll
    for (int k = 0; k < 8; ++k) {
      atomicAdd(&st[tc*8 + k], ssl[k]);
      atomicAdd(&st[128 + tc*8 + k], qql[k]);
    }
  }
  __syncthreads();
  atomicAdd(&acc3g[tid], st[tid]);
}

// ---------- K9: inline BN-coeffs + layer-3 score + top-50 + fused max-pool ----------
__global__ __launch_bounds__(256) void k_top3(
    const float* __restrict__ h3g, const float* __restrict__ acc3,
    const float* __restrict__ g3, const float* __restrict__ be3,
    const float* __restrict__ p3, float* __restrict__ out) {
  __shared__ float sc[128]; __shared__ int si[128]; __shared__ float tv[64];
  __shared__ float scl[128], shl[128], cfl[128];
  __shared__ float red2[4];
  const int tid = threadIdx.x;
  const int b = (blockIdx.x & 7)*32 + (blockIdx.x >> 3);   // XCD-swizzle
  const int wave = tid >> 6, lane = tid & 63;
  float scale = 0.f, shift = 0.f, pv = 0.f;
  if (tid < 128) {                      // inlined fin3
    const float S = acc3[tid], Q = acc3[128 + tid];
    const float N = 25600.f;
    const float mu = S/N, var = Q/N - mu*mu, inv = rsqrtf(var + EPSF);
    scale = inv*g3[tid]; shift = be3[tid] - mu*scale; pv = p3[tid];
    const float t2 = wave_sum(pv*pv);
    if (lane == 0) red2[wave] = t2;
  }
  __syncthreads();
  const float pn = sqrtf(red2[0] + red2[1]);
  if (tid < 128) {
    scl[tid] = scale; shl[tid] = shift; cfl[tid] = scale*pv/pn;
    const float u = wave_sum(shift*pv/pn);
    if (lane == 0) red2[2 + wave] = u;
  }
  __syncthreads();
  const float c30 = red2[2] + red2[3];
  const float clo = cfl[lane], chi = cfl[64 + lane];
  for (int i = wave; i < 100; i += 4) {
    const float* hr = h3g + ((size_t)b*100 + i)*128;
    float v = hr[lane]*clo + hr[64 + lane]*chi;
    v = wave_sum(v);
    if (lane == 0) { sc[i] = v + c30; si[i] = i; }
  }
  if (tid >= 100 && tid < 128) { sc[tid] = -INFINITY; si[tid] = 0x7fffffff; }
  bitonic_desc(sc, si, 128);
  if (tid < 50) tv[tid] = tanhf(sc[tid]);
  __syncthreads();
  if (tid < 128) {
    const float scalev = scl[tid], shiftv = shl[tid];
    float m = -INFINITY;
    for (int k = 0; k < 50; ++k) {
      const float h = h3g[((size_t)b*100 + si[k])*128 + tid];
      m = fmaxf(m, (h*scalev + shiftv)*tv[k]);
    }
    out[(size_t)b*128 + tid] = m;
  }
}

// ---------- host ----------
extern "C" void kernel_launch(void* const* d_in, const int* in_sizes, int n_in,
                              void* d_out, int out_size, void* d_ws, size_t ws_size,
                              hipStream_t stream) {
  (void)in_sizes; (void)n_in; (void)out_size; (void)ws_size;
  const float* data = (const float*)d_in[0];
  const float* W1 = (const float*)d_in[1];
  const float* b1 = (const float*)d_in[2];
  const float* g1 = (const float*)d_in[3];
  const float* be1 = (const float*)d_in[4];
  const float* p1 = (const float*)d_in[5];
  const float* W2 = (const float*)d_in[6];
  const float* b2 = (const float*)d_in[7];
  const float* g2 = (const float*)d_in[8];
  const float* be2 = (const float*)d_in[9];
  const float* p2 = (const float*)d_in[10];
  const float* W3 = (const float*)d_in[11];
  const float* b3 = (const float*)d_in[12];
  const float* g3 = (const float*)d_in[13];
  const float* be3 = (const float*)d_in[14];
  const float* p3 = (const float*)d_in[15];
  float* out = (float*)d_out;

  char* ws = (char*)d_ws;
  size_t off = 0;
  auto alloc = [&](size_t n) { size_t o = off; off += (n + 255) & ~(size_t)255; return o; };
  float* pr     = (float*)(ws + alloc((size_t)BB*49*64*4));
  float* pc     = (float*)(ws + alloc((size_t)BB*49*64*4));
  float* pr2    = (float*)(ws + alloc((size_t)BB*49*64*4));
  float* pc2    = (float*)(ws + alloc((size_t)BB*49*64*4));
  float* s1     = (float*)(ws + alloc((size_t)BB*NN0*4));
  float* accz   = (float*)(ws + alloc(448*4));   // acc1[64] | acc2[128] | acc3[256]
  int*   nodes2 = (int*)  (ws + alloc((size_t)BB*200*4));
  int*   sperm2 = (int*)  (ws + alloc((size_t)BB*200*4));
  float* Y2     = (float*)(ws + alloc((size_t)BB*12800*4));
  float* A2     = (float*)(ws + alloc((size_t)BB*40000*4));
  float* dis2   = (float*)(ws + alloc((size_t)BB*200*4));
  float* h2     = (float*)(ws + alloc((size_t)BB*12800*4));
  int*   nodes3 = (int*)  (ws + alloc((size_t)BB*100*4));
  float* Y3     = (float*)(ws + alloc((size_t)BB*12800*4));
  float* A3     = (float*)(ws + alloc((size_t)BB*10000*4));
  float* dis3   = (float*)(ws + alloc((size_t)BB*100*4));
  float* h3     = (float*)(ws + alloc((size_t)BB*12800*4));
  float* acc1 = accz;
  float* acc2 = accz + 64;
  float* acc3 = accz + 192;

  hipMemsetAsync(accz, 0, 448*4, stream);
  k_tri_mv<<<dim3(BB*7), dim3(256), 0, stream>>>(data, nullptr, nullptr, pr, pc);
  k_tri_mv<<<dim3(BB*7), dim3(256), 0, stream>>>(data, pr, pc, pr2, pc2);
  k_sfin_stats_red<<<dim3(400), dim3(256), 0, stream>>>(pr, pc, pr2, pc2, W1, b1, s1, acc1);
  k_top1<<<dim3(BB), dim3(512), 0, stream>>>(s1, acc1, W1, b1, g1, be1, p1, W2, nodes2, sperm2, Y2);
  k_gatherA2<<<dim3(BB*50), dim3(256), 0, stream>>>(data, nodes2, sperm2, A2, dis2);
  k_conv2<<<dim3(BB), dim3(256), 0, stream>>>(A2, Y2, dis2, b2, h2, acc2);
  k_top2<<<dim3(BB), dim3(512), 0, stream>>>(h2, acc2, g2, be2, p2, W3, nodes2, nodes3, Y3);
  k_gatherA3<<<dim3(BB*25), dim3(256), 0, stream>>>(data, nodes3, A3, dis3);
  k_conv3<<<dim3(BB), dim3(256), 0, stream>>>(A3, Y3, dis3, b3, h3, acc3);
  k_top3<<<dim3(BB), dim3(256), 0, stream>>>(h3, acc3, g3, be3, p3, out);
}